// Round 4
// baseline (46.765 us; speedup 1.0000x reference)
//
#include <hip/hip_runtime.h>
#include <math.h>

#define NCOLS 65536
#define MROWS 256
#define NBINS 512
#define CHUNKS 8
#define CELEMS (NCOLS / CHUNKS)          // 8192 elements per chunk
#define K1_TPB 256
#define K1_ITERS (CELEMS / 4 / K1_TPB)   // 8 float4 iterations per thread
#define ZLO 20.0f
#define INVW ((float)NBINS / (2.0f * ZLO))   // 12.8 bins per unit
#define BINW (2.0f * ZLO / (float)NBINS)     // 0.078125
#define PSCALE 8192.0f
#define CNT_SHIFT 40
#define POS_MASK ((1ull << CNT_SHIFT) - 1ull)

__device__ __forceinline__ float waveReduceSum(float v) {
#pragma unroll
  for (int off = 32; off > 0; off >>= 1) v += __shfl_xor(v, off, 64);
  return v;
}

// ---------------- K1: stream data once; per-chunk packed histogram ----------
__global__ __launch_bounds__(K1_TPB, 8) void hist_kernel(
    const float* __restrict__ logits, const float* __restrict__ pos,
    unsigned long long* __restrict__ gh,
    float* __restrict__ gpos, float* __restrict__ gzp) {
  __shared__ unsigned long long h[NBINS];
  __shared__ float red[8];
  const int blk = blockIdx.x;
  const int row = blk / CHUNKS, chunk = blk % CHUNKS;
  const int tid = threadIdx.x, wid = tid >> 6, lane = tid & 63;

#pragma unroll
  for (int b = tid; b < NBINS; b += K1_TPB) h[b] = 0ull;
  __syncthreads();

  const float4* z4 = (const float4*)(logits + (size_t)row * NCOLS + (size_t)chunk * CELEMS);
  const float4* p4 = (const float4*)(pos + (size_t)row * NCOLS + (size_t)chunk * CELEMS);
  float s_pos = 0.0f, s_zp = 0.0f;

  float4 zr[4], pr[4];
#pragma unroll
  for (int i = 0; i < 4; ++i) {
    zr[i] = z4[i * K1_TPB + tid];
    pr[i] = p4[i * K1_TPB + tid];
  }
#pragma unroll
  for (int i = 0; i < 4; ++i) {
    float4 zv = zr[i], pv = pr[i];
    zr[i] = z4[(i + 4) * K1_TPB + tid];      // prefetch second half
    pr[i] = p4[(i + 4) * K1_TPB + tid];
    float zz[4] = {zv.x, zv.y, zv.z, zv.w};
    float pp[4] = {pv.x, pv.y, pv.z, pv.w};
    s_pos += (pp[0] + pp[1]) + (pp[2] + pp[3]);
    s_zp += zz[0] * pp[0] + zz[1] * pp[1] + zz[2] * pp[2] + zz[3] * pp[3];
#pragma unroll
    for (int c = 0; c < 4; ++c) {
      int b = (int)((zz[c] + ZLO) * INVW);
      b = min(max(b, 0), NBINS - 1);
      unsigned long long pk = (1ull << CNT_SHIFT) |
                              (unsigned long long)__float2int_rn(pp[c] * PSCALE);
      atomicAdd(&h[b], pk);
    }
  }
#pragma unroll
  for (int i = 0; i < 4; ++i) {
    float4 zv = zr[i], pv = pr[i];
    float zz[4] = {zv.x, zv.y, zv.z, zv.w};
    float pp[4] = {pv.x, pv.y, pv.z, pv.w};
    s_pos += (pp[0] + pp[1]) + (pp[2] + pp[3]);
    s_zp += zz[0] * pp[0] + zz[1] * pp[1] + zz[2] * pp[2] + zz[3] * pp[3];
#pragma unroll
    for (int c = 0; c < 4; ++c) {
      int b = (int)((zz[c] + ZLO) * INVW);
      b = min(max(b, 0), NBINS - 1);
      unsigned long long pk = (1ull << CNT_SHIFT) |
                              (unsigned long long)__float2int_rn(pp[c] * PSCALE);
      atomicAdd(&h[b], pk);
    }
  }
  __syncthreads();
#pragma unroll
  for (int b = tid; b < NBINS; b += K1_TPB)
    gh[(size_t)blk * NBINS + b] = h[b];

  s_pos = waveReduceSum(s_pos);
  s_zp = waveReduceSum(s_zp);
  if (lane == 0) { red[wid] = s_pos; red[4 + wid] = s_zp; }
  __syncthreads();
  if (tid == 0) {
    gpos[blk] = (red[0] + red[1]) + (red[2] + red[3]);
    gzp[blk] = (red[4] + red[5]) + (red[6] + red[7]);
  }
}

// ------------- K2: merge + wave-0 Newton (barrier-free) + binned eval -------
#define K2_TPB 256

__global__ __launch_bounds__(K2_TPB) void solve_kernel(
    const unsigned long long* __restrict__ gh,
    const float* __restrict__ gpos, const float* __restrict__ gzp,
    float* __restrict__ rowout) {
  __shared__ unsigned long long hm[NBINS];
  const int row = blockIdx.x;
  const int tid = threadIdx.x;

  // merge 8 chunk histograms; 2 bins per thread, fixed order (deterministic)
#pragma unroll
  for (int j = 0; j < NBINS / K2_TPB; ++j) {
    const int b = tid + j * K2_TPB;
    unsigned long long s = 0ull;
#pragma unroll
    for (int ch = 0; ch < CHUNKS; ++ch)
      s += gh[(size_t)(row * CHUNKS + ch) * NBINS + b];
    hm[b] = s;
  }
  __syncthreads();
  if (tid >= 64) return;                   // wave 0 finishes the row

  const int lane = tid;
  float cnt[8], pb[8], zc[8];
#pragma unroll
  for (int j = 0; j < 8; ++j) {
    const int b = lane + 64 * j;
    const unsigned long long v = hm[b];
    cnt[j] = (float)(unsigned int)(v >> CNT_SHIFT);
    pb[j] = (float)(unsigned long long)(v & POS_MASK) * (1.0f / PSCALE);
    zc[j] = -ZLO + ((float)b + 0.5f) * BINW;
  }
  float Kh = (lane < CHUNKS) ? gpos[row * CHUNKS + lane] : 0.0f;
  float Szp = (lane < CHUNKS) ? gzp[row * CHUNKS + lane] : 0.0f;
  Kh = waveReduceSum(Kh);
  Szp = waveReduceSum(Szp);
  const float K = fminf(fmaxf(Kh * 0.25f, 0.0f), (float)NCOLS);

  float Lb = -2.0f * ZLO, Ub = 2.0f * ZLO, lam = 0.0f;
  for (int it = 0; it < 40; ++it) {
    float fp = 0.0f, sp = 0.0f;
#pragma unroll
    for (int j = 0; j < 8; ++j) {
      const float p = 1.0f / (1.0f + __expf(-(zc[j] + lam)));
      fp += cnt[j] * p;
      sp += cnt[j] * p * (1.0f - p);
    }
    fp = waveReduceSum(fp);
    sp = waveReduceSum(sp);
    const float f = fp - K;
    if (fabsf(f) <= 1e-2f) break;          // wave-uniform
    if (f > 0.0f) Ub = lam; else Lb = lam;
    const float newton = lam - f / (sp + 1e-12f);
    lam = (newton > Lb && newton < Ub) ? newton : 0.5f * (Lb + Ub);
  }

  float tl = 0.0f, ti = 0.0f, tp = 0.0f;
#pragma unroll
  for (int j = 0; j < 8; ++j) {
    const float zs = zc[j] + lam;
    const float e = __expf(-fabsf(zs));
    const float lg = __logf(1.0f + e);
    const float mz = fmaxf(zs, 0.0f);
    const float sig = (zs >= 0.0f) ? (1.0f / (1.0f + e)) : (e / (1.0f + e));
    tl += cnt[j] * (mz + lg);
    ti += pb[j] * sig;
    tp += cnt[j] * sig;
  }
  tl = waveReduceSum(tl);
  ti = waveReduceSum(ti);
  tp = waveReduceSum(tp);
  if (lane == 0) {
    float* o = rowout + row * 4;
    o[0] = 4.0f * tl - (Szp + lam * Kh);   // block-weighted BCE row sum
    o[1] = ti;
    o[2] = tp;
    o[3] = Kh;
  }
}

// ---------------- K3: combine 256 rows into the two scalars -----------------
__global__ void final_kernel(const float* __restrict__ rowout, float* __restrict__ out) {
  const int t = threadIdx.x;               // 256 threads, 4 waves
  const float loss = rowout[t * 4 + 0];
  const float inter = rowout[t * 4 + 1];
  const float psum = rowout[t * 4 + 2];
  const float Kh = rowout[t * 4 + 3];
  float maskc = loss * (1.0f / (512.0f * 512.0f));
  float dicec = 1.0f - (2.0f * inter + 1.0f) / (4.0f * psum + Kh + 1.0f);
  maskc = waveReduceSum(maskc);
  dicec = waveReduceSum(dicec);
  __shared__ float red[8];
  const int wid = t >> 6, lane = t & 63;
  if (lane == 0) { red[wid] = maskc; red[4 + wid] = dicec; }
  __syncthreads();
  if (t == 0) {
    float a = 0.0f, b = 0.0f;
    for (int j = 0; j < 4; ++j) { a += red[j]; b += red[4 + j]; }
    out[0] = a / 256.0f;
    out[1] = b / 256.0f;
  }
}

// -------- fallback (round-2 style, 4 KB ws) in case ws is too small ---------
#define FB_TPB 1024
#define FB_NV4 (NCOLS / 4 / FB_TPB)
__device__ __forceinline__ void fbReduce2(float a, float b, float* red,
                                          int wid, int lane, float& A, float& B) {
  a = waveReduceSum(a);
  b = waveReduceSum(b);
  __syncthreads();
  if (lane == 0) { red[wid] = a; red[16 + wid] = b; }
  __syncthreads();
  float ta = 0.0f, tb = 0.0f;
#pragma unroll
  for (int j = 0; j < 16; ++j) { ta += red[j]; tb += red[16 + j]; }
  A = ta; B = tb;
}

__global__ __launch_bounds__(FB_TPB) void fb_row_kernel(
    const float* __restrict__ logits, const float* __restrict__ pos,
    float* __restrict__ rowout) {
  __shared__ unsigned int h_cnt[2048];
  __shared__ int h_sum[2048];
  __shared__ float red[64];
  const int row = blockIdx.x;
  const int tid = threadIdx.x, wid = tid >> 6, lane = tid & 63;
  const float4* z4 = (const float4*)(logits + (size_t)row * NCOLS);
  const float4* p4 = (const float4*)(pos + (size_t)row * NCOLS);
  for (int b = tid; b < 2048; b += FB_TPB) { h_cnt[b] = 0u; h_sum[b] = 0; }
  __syncthreads();
  const float invw = 2048.0f / 40.0f;
  float s_pos = 0.0f;
#pragma unroll
  for (int i = 0; i < FB_NV4; ++i) {
    float4 zv = z4[i * FB_TPB + tid];
    float4 pv = p4[i * FB_TPB + tid];
    s_pos += (pv.x + pv.y) + (pv.z + pv.w);
    float zz[4] = {zv.x, zv.y, zv.z, zv.w};
#pragma unroll
    for (int c = 0; c < 4; ++c) {
      int b = (int)((zz[c] + 20.0f) * invw);
      b = min(max(b, 0), 2047);
      atomicAdd(&h_cnt[b], 1u);
      atomicAdd(&h_sum[b], __float2int_rn(zz[c] * 1024.0f));
    }
  }
  float K_high, dummy;
  fbReduce2(s_pos, 0.0f, red, wid, lane, K_high, dummy);
  float K = fminf(fmaxf(K_high * 0.25f, 0.0f), (float)NCOLS);
  const float c0 = (float)h_cnt[tid];
  const float c1 = (float)h_cnt[tid + FB_TPB];
  const float zb0 = (c0 > 0.0f) ? (float)h_sum[tid] / (1024.0f * c0) : 0.0f;
  const float zb1 = (c1 > 0.0f) ? (float)h_sum[tid + FB_TPB] / (1024.0f * c1) : 0.0f;
  float Lb = -40.0f, Ub = 40.0f, lam = 0.0f;
  for (int it = 0; it < 40; ++it) {
    float p0 = 1.0f / (1.0f + __expf(-(zb0 + lam)));
    float p1 = 1.0f / (1.0f + __expf(-(zb1 + lam)));
    float F, S;
    fbReduce2(c0 * p0 + c1 * p1, c0 * p0 * (1.0f - p0) + c1 * p1 * (1.0f - p1),
              red, wid, lane, F, S);
    float f = F - K;
    if (fabsf(f) <= 1e-3f) break;
    if (f > 0.0f) Ub = lam; else Lb = lam;
    float newton = lam - f / (S + 1e-12f);
    lam = (newton > Lb && newton < Ub) ? newton : 0.5f * (Lb + Ub);
  }
  float loss = 0.0f, inter = 0.0f, psum = 0.0f;
#pragma unroll
  for (int i = 0; i < FB_NV4; ++i) {
    float4 zv = z4[i * FB_TPB + tid];
    float4 pv = p4[i * FB_TPB + tid];
    float zz[4] = {zv.x, zv.y, zv.z, zv.w};
    float pp[4] = {pv.x, pv.y, pv.z, pv.w};
#pragma unroll
    for (int c = 0; c < 4; ++c) {
      float zs = zz[c] + lam;
      float q = __expf(-fabsf(zs));
      loss += 4.0f * fmaxf(zs, 0.0f) - zs * pp[c] + 4.0f * __logf(1.0f + q);
      float sig = (zs >= 0.0f) ? (1.0f / (1.0f + q)) : (q / (1.0f + q));
      inter += sig * pp[c];
      psum += sig;
    }
  }
  float TL, TI;
  fbReduce2(loss, inter, red, wid, lane, TL, TI);
  float TP, d2;
  fbReduce2(psum, 0.0f, red, wid, lane, TP, d2);
  if (tid == 0) {
    float* o = rowout + row * 4;
    o[0] = TL; o[1] = TI; o[2] = TP; o[3] = K_high;
  }
}

extern "C" void kernel_launch(void* const* d_in, const int* in_sizes, int n_in,
                              void* d_out, int out_size, void* d_ws, size_t ws_size,
                              hipStream_t stream) {
  const float* logits = (const float*)d_in[0];
  const float* pos = (const float*)d_in[1];
  char* ws = (char*)d_ws;

  const size_t nblk = (size_t)MROWS * CHUNKS;
  const size_t off_gh = 0;
  const size_t off_gpos = off_gh + nblk * NBINS * sizeof(unsigned long long);
  const size_t off_gzp = off_gpos + nblk * sizeof(float);
  const size_t off_rowout = off_gzp + nblk * sizeof(float);
  const size_t needed = off_rowout + (size_t)MROWS * 4 * sizeof(float);

  if (ws_size >= needed) {
    unsigned long long* gh = (unsigned long long*)(ws + off_gh);
    float* gpos = (float*)(ws + off_gpos);
    float* gzp = (float*)(ws + off_gzp);
    float* rowout = (float*)(ws + off_rowout);
    hist_kernel<<<(int)nblk, K1_TPB, 0, stream>>>(logits, pos, gh, gpos, gzp);
    solve_kernel<<<MROWS, K2_TPB, 0, stream>>>(gh, gpos, gzp, rowout);
    final_kernel<<<1, 256, 0, stream>>>(rowout, (float*)d_out);
  } else {
    float* rowout = (float*)d_ws;          // 4 KB fallback path
    fb_row_kernel<<<MROWS, FB_TPB, 0, stream>>>(logits, pos, rowout);
    final_kernel<<<1, 256, 0, stream>>>(rowout, (float*)d_out);
  }
}